// Round 7
// baseline (207.758 us; speedup 1.0000x reference)
//
#include <hip/hip_runtime.h>

// SynthMorphLoss: soft-dice over int32 label maps + diffusion regularizer.
// B=1, D=160, H=192, W=224, 26 classes (class 0 ignored in dice mean).
// R7: A/B the two load paths against the measured ~2.05 TB/s lane-byte
// ceiling (validated R1-R6, occupancy-independent):
//  - hist: global_load_lds DMA staging (bypasses VMEM->VGPR return path;
//    m97 GEMM sustained ~13.7 TB/s on this path).
//  - diff: stays on VGPR path; SLAB=3 x DCH=10 + LDS halo exchange cuts
//    re-load factor 1.37x -> 1.18x (113 -> 98 MB lane bytes).

namespace {
constexpr int NC    = 26;
constexpr int Dd    = 160, Hh = 192, Ww = 224;
constexpr int W4    = Ww / 4;                 // 56 float4 per row
constexpr int PL4   = Hh * W4;                // 10752 float4 per (c,d) plane
constexpr int N4L   = Dd * Hh * Ww / 4;       // 1,720,320 int4 per label map
constexpr int JSTRIDE = 33;                   // joint-hist row stride
constexpr int NBINS   = NC * JSTRIDE;         // 858
constexpr int HIST_BLOCKS = 960;              // 960*256*7 == N4L exact
constexpr int HIST_ITERS  = 7;
// diff decomposition: wave owns (c, 3-row h-slab, 10-plane d-chunk)
constexpr int SLAB    = 3;
constexpr int SLABS   = Hh / SLAB;            // 64
constexpr int SGRPS   = SLABS / 4;            // 16 (4 waves/block, adjacent)
constexpr int DCH     = 10;
constexpr int DCHUNKS = Dd / DCH;             // 16
constexpr int DIFF_BLOCKS = 3 * DCHUNKS * SGRPS;   // 768 == 3/CU balanced
}

typedef __attribute__((address_space(1))) const void* gva_t;
typedef __attribute__((address_space(3))) void* lva_t;

__global__ void init_ws_kernel(unsigned int* __restrict__ joint,
                               double* __restrict__ sums) {
    int i = blockIdx.x * blockDim.x + threadIdx.x;
    if (i < NBINS) joint[i] = 0u;
    if (i < 3)     sums[i]  = 0.0;
}

// Joint histogram via global_load_lds DMA staging: per iter each wave DMAs
// 64 int4 from f and 64 from m straight into LDS (no VGPR round-trip),
// barrier (drains vmcnt), ds_read_b128 back, 4 joint-bin LDS atomics.
__global__ __launch_bounds__(256) void hist_kernel(
        const int4* __restrict__ f4,
        const int4* __restrict__ m4,
        unsigned int* __restrict__ gj) {
    __shared__ int4 sf[256];
    __shared__ int4 sm[256];
    __shared__ unsigned int h[NBINS];
    for (int i = threadIdx.x; i < NBINS; i += 256) h[i] = 0u;

    const int wid = threadIdx.x >> 6;
    int base = blockIdx.x * (HIST_ITERS * 256);

    for (int it = 0; it < HIST_ITERS; ++it) {
        // wave-uniform LDS base + lane*16 scatter (m104 layout rule)
        __builtin_amdgcn_global_load_lds((gva_t)(f4 + base + threadIdx.x),
                                         (lva_t)(sf + wid * 64), 16, 0, 0);
        __builtin_amdgcn_global_load_lds((gva_t)(m4 + base + threadIdx.x),
                                         (lva_t)(sm + wid * 64), 16, 0, 0);
        __syncthreads();   // drains vmcnt(0) incl. the DMA loads
        int4 a = sf[threadIdx.x];
        int4 b = sm[threadIdx.x];
        atomicAdd(&h[a.x * JSTRIDE + b.x], 1u);
        atomicAdd(&h[a.y * JSTRIDE + b.y], 1u);
        atomicAdd(&h[a.z * JSTRIDE + b.z], 1u);
        atomicAdd(&h[a.w * JSTRIDE + b.w], 1u);
        __syncthreads();   // protect sf/sm before next iter's DMA overwrite
        base += 256;
    }

    for (int i = threadIdx.x; i < NBINS; i += 256) {
        unsigned int v = h[i];
        if (v) atomicAdd(&gj[i], v);
    }
}

// z-carry diffusion with LDS halo exchange. Wave wid of block b owns h-slab
// [h0,h0+3) of channel c, planes d0..d0+9. Carries 3 current-plane rows in
// registers; per d-step loads 3 next-plane rows; the dy halo row comes from
// wave wid+1's p0 via LDS (only wid==3 loads it from global).
__global__ __launch_bounds__(256, 3) void diff_kernel(
        const float4* __restrict__ v4,
        double* __restrict__ gs) {
    __shared__ float4 halo[4][W4];
    __shared__ float px[4], py[4], pz[4];

    const int lane = threadIdx.x & 63;
    const int wid  = threadIdx.x >> 6;
    const int b    = blockIdx.x;
    const int c      = b / (DCHUNKS * SGRPS);      // b / 256
    const int rem    = b % (DCHUNKS * SGRPS);
    const int dchunk = rem / SGRPS;
    const int sgrp   = rem % SGRPS;
    const int slab   = sgrp * 4 + wid;
    const int h0     = slab * SLAB;
    const int d0     = dchunk * DCH;
    const bool al    = (lane < W4);
    const bool hv    = (slab < SLABS - 1);         // dy halo row exists
    const int  l     = al ? lane : (W4 - 1);       // clamp inactive lanes

    size_t cur = ((size_t)(c * Dd + d0) * Hh + h0) * W4 + l;

    float4 p0 = v4[cur];
    float4 p1 = v4[cur + W4];
    float4 p2 = v4[cur + 2 * W4];

    float sx = 0.f, sy = 0.f, sz = 0.f;

    for (int k = 0; k < DCH; ++k) {
        const bool dzv = (d0 + k < Dd - 1);        // wave-uniform
        // publish current p0 for the wave above (slab-1 = wid-1)
        if (al) halo[wid][lane] = p0;
        float4 hl = p2;                             // dummy for hv==false
        if (wid == 3 && hv) hl = v4[cur + SLAB * W4];
        // next plane rows (dz + next iteration's current)
        float4 n0 = p0, n1 = p1, n2 = p2;
        if (dzv) {
            n0 = v4[cur + PL4];
            n1 = v4[cur + PL4 + W4];
            n2 = v4[cur + PL4 + 2 * W4];
        }
        __syncthreads();
        if (wid < 3) hl = halo[wid + 1][l];

        // dx: 3 interior diffs + crossing diff per row (lane mask)
#define DX(P)                                                                  \
        {                                                                      \
            float d1 = (P).y - (P).x, d2 = (P).z - (P).y, d3 = (P).w - (P).z;  \
            sx += d1 * d1 + d2 * d2 + d3 * d3;                                 \
            float nx = __shfl_down((P).x, 1);                                  \
            float d4 = nx - (P).w;                                             \
            sx += (lane < W4 - 1) ? d4 * d4 : 0.f;                             \
        }
        DX(p0) DX(p1) DX(p2)
#undef DX
#define DY(A, B)                                                               \
        {                                                                      \
            float e0 = (B).x - (A).x, e1 = (B).y - (A).y;                      \
            float e2 = (B).z - (A).z, e3 = (B).w - (A).w;                      \
            sy += e0 * e0 + e1 * e1 + e2 * e2 + e3 * e3;                       \
        }
        DY(p0, p1) DY(p1, p2)
        if (hv) DY(p2, hl)
#undef DY
        if (dzv) {
#define DZ(A, B)                                                               \
            {                                                                  \
                float e0 = (B).x - (A).x, e1 = (B).y - (A).y;                  \
                float e2 = (B).z - (A).z, e3 = (B).w - (A).w;                  \
                sz += e0 * e0 + e1 * e1 + e2 * e2 + e3 * e3;                   \
            }
            DZ(p0, n0) DZ(p1, n1) DZ(p2, n2)
#undef DZ
        }
        __syncthreads();   // all reads of halo[] done before next write
        p0 = n0; p1 = n1; p2 = n2;
        cur += PL4;
    }

    if (!al) { sx = 0.f; sy = 0.f; sz = 0.f; }     // clamped lanes: drop dupes

    #pragma unroll
    for (int off = 32; off > 0; off >>= 1) {
        sx += __shfl_down(sx, off);
        sy += __shfl_down(sy, off);
        sz += __shfl_down(sz, off);
    }
    if (lane == 0) { px[wid] = sx; py[wid] = sy; pz[wid] = sz; }
    __syncthreads();
    if (threadIdx.x == 0) {
        atomicAdd(&gs[0], (double)(px[0] + px[1] + px[2] + px[3]));
        atomicAdd(&gs[1], (double)(py[0] + py[1] + py[2] + py[3]));
        atomicAdd(&gs[2], (double)(pz[0] + pz[1] + pz[2] + pz[3]));
    }
}

__global__ void finalize_kernel(const unsigned int* __restrict__ gj,
                                const double* __restrict__ gs,
                                float* __restrict__ out) {
    int lane = threadIdx.x & 63;
    float term = 0.f;
    if (lane >= 1 && lane < NC) {
        float fv = 0.f, mv = 0.f;
        #pragma unroll
        for (int m = 0; m < NC; ++m) fv += (float)gj[lane * JSTRIDE + m];
        #pragma unroll
        for (int f = 0; f < NC; ++f) mv += (float)gj[f * JSTRIDE + lane];
        float iv = (float)gj[lane * JSTRIDE + lane];
        term = (2.f * iv + 1e-5f) / (fv + mv + 1e-5f);
    }
    #pragma unroll
    for (int off = 32; off > 0; off >>= 1) term += __shfl_down(term, off);
    if (threadIdx.x == 0 && blockIdx.x == 0) {
        float sim = 1.f - term * (1.f / 25.f);
        double mdx = gs[0] / ((double)3 * Dd * Hh * (Ww - 1));
        double mdy = gs[1] / ((double)3 * Dd * (Hh - 1) * Ww);
        double mdz = gs[2] / ((double)3 * (Dd - 1) * Hh * Ww);
        float smooth = (float)((mdx + mdy + mdz) / 3.0);
        out[0] = sim + smooth;
        out[1] = sim;
        out[2] = smooth;
    }
}

extern "C" void kernel_launch(void* const* d_in, const int* in_sizes, int n_in,
                              void* d_out, int out_size, void* d_ws, size_t ws_size,
                              hipStream_t stream) {
    const int*   fl = (const int*)d_in[0];
    const int*   ml = (const int*)d_in[1];
    const float* vf = (const float*)d_in[2];
    float* out = (float*)d_out;

    // workspace: [0, 3432) joint counts (858 uints); [3584, 3608) double sums[3]
    unsigned int* joint = (unsigned int*)d_ws;
    double*       sums  = (double*)((char*)d_ws + 3584);

    init_ws_kernel<<<1, 1024, 0, stream>>>(joint, sums);
    hist_kernel<<<HIST_BLOCKS, 256, 0, stream>>>((const int4*)fl, (const int4*)ml, joint);
    diff_kernel<<<DIFF_BLOCKS, 256, 0, stream>>>((const float4*)vf, sums);
    finalize_kernel<<<1, 64, 0, stream>>>(joint, sums, out);
}

// Round 8
// 205.070 us; speedup vs baseline: 1.0131x; 1.0131x over previous
//
#include <hip/hip_runtime.h>

// SynthMorphLoss: soft-dice over int32 label maps + diffusion regularizer.
// B=1, D=160, H=192, W=224, 26 classes (class 0 ignored in dice mean).
// R8: hist rebuilt as a wave-private global_load_lds pipeline (depth 4,
// manual s_waitcnt vmcnt(6), NO __syncthreads in the stream loop) to test
// whether the DMA path beats the ~2 TB/s per-CU VGPR-return ceiling
// (R1-R7 invariant; R7's DMA test was invalidated by vmcnt(0) barriers).
// diff unchanged from R7 for attribution.

namespace {
constexpr int NC    = 26;
constexpr int Dd    = 160, Hh = 192, Ww = 224;
constexpr int W4    = Ww / 4;                 // 56 float4 per row
constexpr int PL4   = Hh * W4;                // 10752 float4 per (c,d) plane
constexpr int N4L   = Dd * Hh * Ww / 4;       // 1,720,320 int4 per label map
constexpr int JSTRIDE = 33;                   // joint-hist row stride
constexpr int NBINS   = NC * JSTRIDE;         // 858
constexpr int HIST_BLOCKS = 840;              // 840 * 2048 == N4L exact
constexpr int TILES_PER_WAVE = 8;             // 8 tiles x 64 int4 = 512/wave
// diff decomposition: wave owns (c, 3-row h-slab, 10-plane d-chunk)
constexpr int SLAB    = 3;
constexpr int SLABS   = Hh / SLAB;            // 64
constexpr int SGRPS   = SLABS / 4;            // 16 (4 waves/block, adjacent)
constexpr int DCH     = 10;
constexpr int DCHUNKS = Dd / DCH;             // 16
constexpr int DIFF_BLOCKS = 3 * DCHUNKS * SGRPS;   // 768 == 3/CU balanced
}

typedef __attribute__((address_space(1))) const void* gva_t;
typedef __attribute__((address_space(3))) void* lva_t;

// wait until at most N vector-memory ops outstanding (expcnt/lgkmcnt masked)
#define WAITVM(n) __builtin_amdgcn_s_waitcnt(0x0F70 | (n))

__global__ void init_ws_kernel(unsigned int* __restrict__ joint,
                               double* __restrict__ sums) {
    int i = blockIdx.x * blockDim.x + threadIdx.x;
    if (i < NBINS) joint[i] = 0u;
    if (i < 3)     sums[i]  = 0.0;
}

// Joint histogram, wave-private DMA pipeline. Each wave streams 8 tiles of
// 64 int4 from each map through 4 private LDS buffers; steady state keeps
// 8 DMA loads in flight and waits vmcnt(6) before consuming the oldest.
__global__ __launch_bounds__(256) void hist_kernel(
        const int4* __restrict__ f4,
        const int4* __restrict__ m4,
        unsigned int* __restrict__ gj) {
    __shared__ int4 fbuf[4][4][64];          // [wave][depth][lane]
    __shared__ int4 mbuf[4][4][64];
    __shared__ unsigned int h[NBINS];
    for (int i = threadIdx.x; i < NBINS; i += 256) h[i] = 0u;
    __syncthreads();

    const int lane = threadIdx.x & 63;
    const int wid  = threadIdx.x >> 6;
    const int base = blockIdx.x * 2048 + wid * 512;   // int4 index, per wave

#define ISSUE(T)                                                               \
    __builtin_amdgcn_global_load_lds((gva_t)(f4 + base + (T) * 64 + lane),     \
                                     (lva_t)&fbuf[wid][(T) & 3][0], 16, 0, 0); \
    __builtin_amdgcn_global_load_lds((gva_t)(m4 + base + (T) * 64 + lane),     \
                                     (lva_t)&mbuf[wid][(T) & 3][0], 16, 0, 0);

    // prologue: 3 tile-pairs in flight
    ISSUE(0) ISSUE(1) ISSUE(2)

    #pragma unroll
    for (int it = 0; it < TILES_PER_WAVE; ++it) {
        if (it + 3 < TILES_PER_WAVE) { ISSUE(it + 3) }
        // outstanding newer tile-pairs after issue: min(8,it+4)-1-it
        const int newer = ((it + 4 < TILES_PER_WAVE) ? (it + 4)
                                                     : TILES_PER_WAVE) - 1 - it;
        switch (2 * newer) {           // constant per unrolled iteration
            case 6: WAITVM(6); break;
            case 4: WAITVM(4); break;
            case 2: WAITVM(2); break;
            default: WAITVM(0); break;
        }
        int4 a = fbuf[wid][it & 3][lane];
        int4 b = mbuf[wid][it & 3][lane];
        atomicAdd(&h[a.x * JSTRIDE + b.x], 1u);
        atomicAdd(&h[a.y * JSTRIDE + b.y], 1u);
        atomicAdd(&h[a.z * JSTRIDE + b.z], 1u);
        atomicAdd(&h[a.w * JSTRIDE + b.w], 1u);
    }
#undef ISSUE

    __syncthreads();
    for (int i = threadIdx.x; i < NBINS; i += 256) {
        unsigned int v = h[i];
        if (v) atomicAdd(&gj[i], v);
    }
}

// z-carry diffusion with LDS halo exchange (unchanged from R7).
__global__ __launch_bounds__(256, 3) void diff_kernel(
        const float4* __restrict__ v4,
        double* __restrict__ gs) {
    __shared__ float4 halo[4][W4];
    __shared__ float px[4], py[4], pz[4];

    const int lane = threadIdx.x & 63;
    const int wid  = threadIdx.x >> 6;
    const int b    = blockIdx.x;
    const int c      = b / (DCHUNKS * SGRPS);      // b / 256
    const int rem    = b % (DCHUNKS * SGRPS);
    const int dchunk = rem / SGRPS;
    const int sgrp   = rem % SGRPS;
    const int slab   = sgrp * 4 + wid;
    const int h0     = slab * SLAB;
    const int d0     = dchunk * DCH;
    const bool al    = (lane < W4);
    const bool hv    = (slab < SLABS - 1);         // dy halo row exists
    const int  l     = al ? lane : (W4 - 1);       // clamp inactive lanes

    size_t cur = ((size_t)(c * Dd + d0) * Hh + h0) * W4 + l;

    float4 p0 = v4[cur];
    float4 p1 = v4[cur + W4];
    float4 p2 = v4[cur + 2 * W4];

    float sx = 0.f, sy = 0.f, sz = 0.f;

    for (int k = 0; k < DCH; ++k) {
        const bool dzv = (d0 + k < Dd - 1);        // wave-uniform
        if (al) halo[wid][lane] = p0;
        float4 hl = p2;                             // dummy for hv==false
        if (wid == 3 && hv) hl = v4[cur + SLAB * W4];
        float4 n0 = p0, n1 = p1, n2 = p2;
        if (dzv) {
            n0 = v4[cur + PL4];
            n1 = v4[cur + PL4 + W4];
            n2 = v4[cur + PL4 + 2 * W4];
        }
        __syncthreads();
        if (wid < 3) hl = halo[wid + 1][l];

#define DX(P)                                                                  \
        {                                                                      \
            float d1 = (P).y - (P).x, d2 = (P).z - (P).y, d3 = (P).w - (P).z;  \
            sx += d1 * d1 + d2 * d2 + d3 * d3;                                 \
            float nx = __shfl_down((P).x, 1);                                  \
            float d4 = nx - (P).w;                                             \
            sx += (lane < W4 - 1) ? d4 * d4 : 0.f;                             \
        }
        DX(p0) DX(p1) DX(p2)
#undef DX
#define DY(A, B)                                                               \
        {                                                                      \
            float e0 = (B).x - (A).x, e1 = (B).y - (A).y;                      \
            float e2 = (B).z - (A).z, e3 = (B).w - (A).w;                      \
            sy += e0 * e0 + e1 * e1 + e2 * e2 + e3 * e3;                       \
        }
        DY(p0, p1) DY(p1, p2)
        if (hv) DY(p2, hl)
#undef DY
        if (dzv) {
#define DZ(A, B)                                                               \
            {                                                                  \
                float e0 = (B).x - (A).x, e1 = (B).y - (A).y;                  \
                float e2 = (B).z - (A).z, e3 = (B).w - (A).w;                  \
                sz += e0 * e0 + e1 * e1 + e2 * e2 + e3 * e3;                   \
            }
            DZ(p0, n0) DZ(p1, n1) DZ(p2, n2)
#undef DZ
        }
        __syncthreads();
        p0 = n0; p1 = n1; p2 = n2;
        cur += PL4;
    }

    if (!al) { sx = 0.f; sy = 0.f; sz = 0.f; }

    #pragma unroll
    for (int off = 32; off > 0; off >>= 1) {
        sx += __shfl_down(sx, off);
        sy += __shfl_down(sy, off);
        sz += __shfl_down(sz, off);
    }
    if (lane == 0) { px[wid] = sx; py[wid] = sy; pz[wid] = sz; }
    __syncthreads();
    if (threadIdx.x == 0) {
        atomicAdd(&gs[0], (double)(px[0] + px[1] + px[2] + px[3]));
        atomicAdd(&gs[1], (double)(py[0] + py[1] + py[2] + py[3]));
        atomicAdd(&gs[2], (double)(pz[0] + pz[1] + pz[2] + pz[3]));
    }
}

__global__ void finalize_kernel(const unsigned int* __restrict__ gj,
                                const double* __restrict__ gs,
                                float* __restrict__ out) {
    int lane = threadIdx.x & 63;
    float term = 0.f;
    if (lane >= 1 && lane < NC) {
        float fv = 0.f, mv = 0.f;
        #pragma unroll
        for (int m = 0; m < NC; ++m) fv += (float)gj[lane * JSTRIDE + m];
        #pragma unroll
        for (int f = 0; f < NC; ++f) mv += (float)gj[f * JSTRIDE + lane];
        float iv = (float)gj[lane * JSTRIDE + lane];
        term = (2.f * iv + 1e-5f) / (fv + mv + 1e-5f);
    }
    #pragma unroll
    for (int off = 32; off > 0; off >>= 1) term += __shfl_down(term, off);
    if (threadIdx.x == 0 && blockIdx.x == 0) {
        float sim = 1.f - term * (1.f / 25.f);
        double mdx = gs[0] / ((double)3 * Dd * Hh * (Ww - 1));
        double mdy = gs[1] / ((double)3 * Dd * (Hh - 1) * Ww);
        double mdz = gs[2] / ((double)3 * (Dd - 1) * Hh * Ww);
        float smooth = (float)((mdx + mdy + mdz) / 3.0);
        out[0] = sim + smooth;
        out[1] = sim;
        out[2] = smooth;
    }
}

extern "C" void kernel_launch(void* const* d_in, const int* in_sizes, int n_in,
                              void* d_out, int out_size, void* d_ws, size_t ws_size,
                              hipStream_t stream) {
    const int*   fl = (const int*)d_in[0];
    const int*   ml = (const int*)d_in[1];
    const float* vf = (const float*)d_in[2];
    float* out = (float*)d_out;

    // workspace: [0, 3432) joint counts (858 uints); [3584, 3608) double sums[3]
    unsigned int* joint = (unsigned int*)d_ws;
    double*       sums  = (double*)((char*)d_ws + 3584);

    init_ws_kernel<<<1, 1024, 0, stream>>>(joint, sums);
    hist_kernel<<<HIST_BLOCKS, 256, 0, stream>>>((const int4*)fl, (const int4*)ml, joint);
    diff_kernel<<<DIFF_BLOCKS, 256, 0, stream>>>((const float4*)vf, sums);
    finalize_kernel<<<1, 64, 0, stream>>>(joint, sums, out);
}